// Round 1
// 412.513 us; speedup vs baseline: 1.1088x; 1.1088x over previous
//
#include <hip/hip_runtime.h>

typedef __attribute__((ext_vector_type(8))) short short8;
typedef __attribute__((ext_vector_type(4))) float f32x4;

#define C_ 32
#define T_ 2048
#define K_ 129

__device__ __forceinline__ unsigned int bfround(float f) {
    unsigned int u = __float_as_uint(f);
    return u + 0x7fffu + ((u >> 16) & 1u);   // RNE bf16 in high 16 bits
}

// ---- k0: pack Toeplitz-W A-fragments into d_ws ----
// A_{c,d,iq,igl}[m, k=(i2,tl)] = bf16( sw[c, iq*8+igl*2+i2, 16d+64+m-tl] ), j-OOB = 0
__global__ __launch_bounds__(256) void wtoep_pack(
    const float* __restrict__ sw, unsigned short* __restrict__ wt)
{
    const int c = blockIdx.x, dd = blockIdx.y;     // 32 x 9
    const int t = threadIdx.x, l = t & 63, fw = t >> 6;
    const int m = l & 15, qb = (l >> 4) & 1, i2 = (l >> 5) & 1;
    const int d = dd - 4;
    for (int fr = fw; fr < 32; fr += 4) {          // fr = iq*4 + igl
        const int iq = fr >> 2, igl = fr & 3;
        const int i = iq * 8 + igl * 2 + i2;
        unsigned short v[8];
        #pragma unroll
        for (int e = 0; e < 8; ++e) {
            const int tl = 8 * qb + e;
            const int j = 16 * d + 64 + m - tl;
            const float wv = (j >= 0 && j <= 128) ? sw[(c * 64 + i) * K_ + j] : 0.f;
            v[e] = (unsigned short)(bfround(wv) >> 16);
        }
        *(short8*)(wt + (((c * 9 + dd) * 32 + fr) * 64 + l) * 8) = *(short8*)v;
    }
}

// ---- k2: scatter-form batched-b MFMA conv ----
// Each block owns z-tiles [g0, g0+4) for one channel c, reads coeffs exactly once
// (no halo), and scatters A_d * z_v into out tiles o = v + d - 4 via f32 atomics.
__global__ __launch_bounds__(256, 3) void wavelet_synth_v5(
    const float* __restrict__ coeffs, const int* __restrict__ rows,
    const int* __restrict__ cols, const float* __restrict__ ri_scale,
    const float* __restrict__ ri_shift, const float* __restrict__ freq_gain,
    const unsigned short* __restrict__ wt, float* __restrict__ out)
{
    // zs: 4 vtiles x 8 il x 16 b rows, 16 tau bf16 padded to 24 ushorts = 24576 B
    // red (aliased, used after compute): 4 waves x 12 tiles x 64 lanes x 4 f32 = 49152 B
    __shared__ __align__(16) unsigned char smem[49152];
    unsigned short* zs = (unsigned short*)smem;

    const int t  = threadIdx.x;
    const int g0 = blockIdx.x * 4;      // owned z-tiles g0..g0+3 (always in [0,128))
    const int c  = blockIdx.y;
    const int rc = rows[c];
    const int cc = cols[c];

    const int lane = t & 63;
    const int w    = t >> 6;            // wave id = igl
    const int i2   = (lane >> 5) & 1;
    const int qb   = (lane >> 4) & 1;

    // staging decomposition: thread -> (r half, batch, il)
    const int s_r  = t & 1;
    const int s_b  = (t >> 1) & 15;
    const int s_il = (t >> 5) & 7;

    f32x4 acc[12];
    #pragma unroll
    for (int a = 0; a < 12; ++a) acc[a] = (f32x4){0.f, 0.f, 0.f, 0.f};

    for (int iq = 0; iq < 8; ++iq) {
        // per-iq affine constants for this thread's staging rows
        const int i  = iq * 8 + s_il;
        const int f  = i & 31;
        const int ri = i >> 5;
        const float inv = __builtin_amdgcn_rcpf(ri_scale[f] + 1e-12f);
        const float Aa  = inv * freq_gain[f];
        const float Bb  = -ri_shift[f] * freq_gain[f];
        const long  row = ((long)(s_b * 2 + ri) * 32 + f) * 35 + rc * 5 + cc;
        const float* srcb = coeffs + row * T_ + g0 * 16 + s_r * 8;

        __syncthreads();   // previous phase's zs reads done before overwrite
        #pragma unroll
        for (int vi = 0; vi < 4; ++vi) {
            const float4 x = *(const float4*)(srcb + vi * 16);
            const float4 y = *(const float4*)(srcb + vi * 16 + 4);
            float vv[8];
            vv[0] = x.x * Aa + Bb; vv[1] = x.y * Aa + Bb;
            vv[2] = x.z * Aa + Bb; vv[3] = x.w * Aa + Bb;
            vv[4] = y.x * Aa + Bb; vv[5] = y.y * Aa + Bb;
            vv[6] = y.z * Aa + Bb; vv[7] = y.w * Aa + Bb;
            unsigned short pk[8];
            #pragma unroll
            for (int e = 0; e < 8; ++e) pk[e] = (unsigned short)(bfround(vv[e]) >> 16);
            *(short8*)(zs + ((vi * 8 + s_il) * 16 + s_b) * 24 + s_r * 8) = *(short8*)pk;
        }
        __syncthreads();

        // compute: 9 d-shifts x 4 owned z-tiles -> acc[vi + d]
        const unsigned short* wbase = wt + ((c * 9) * 32 + iq * 4 + w) * 512 + lane * 8;
        const unsigned short* zb =
            zs + ((w * 2 + i2) * 16 + (lane & 15)) * 24 + qb * 8;
        #pragma unroll
        for (int d = 0; d < 9; ++d) {
            const short8 afrag = *(const short8*)(wbase + d * 32 * 512);
            #pragma unroll
            for (int vi = 0; vi < 4; ++vi) {
                const short8 bf = *(const short8*)(zb + vi * (8 * 16 * 24));
                acc[vi + d] = __builtin_amdgcn_mfma_f32_16x16x32_bf16(
                    afrag, bf, acc[vi + d], 0, 0, 0);
            }
        }
    }

    // ---- cross-wave reduce + atomic scatter to out ----
    __syncthreads();
    float* red = (float*)smem;
    #pragma unroll
    for (int a = 0; a < 12; ++a)
        *(f32x4*)(red + ((w * 12 + a) * 64 + lane) * 4) = acc[a];
    __syncthreads();

    {
        const int rb  = t >> 4;          // batch 0..15
        const int tau = t & 15;          // tau within tile (contiguous per 16 lanes)
        const int s   = tau >> 2;
        const int rr  = tau & 3;
        float* obase = out + ((long)rb * C_ + c) * T_ + tau;
        #pragma unroll
        for (int a = 0; a < 12; ++a) {
            const int o = g0 - 4 + a;    // absolute out tile
            if (o < 0 || o >= 128) continue;
            float sum = 0.f;
            #pragma unroll
            for (int ww = 0; ww < 4; ++ww)
                sum += red[((ww * 12 + a) * 64 + s * 16 + rb) * 4 + rr];
            unsafeAtomicAdd(obase + o * 16, sum);
        }
    }
}

extern "C" void kernel_launch(void* const* d_in, const int* in_sizes, int n_in,
                              void* d_out, int out_size, void* d_ws, size_t ws_size,
                              hipStream_t stream) {
    const float* coeffs    = (const float*)d_in[0];
    const int*   rows      = (const int*)d_in[1];
    const int*   cols      = (const int*)d_in[2];
    const float* ri_scale  = (const float*)d_in[3];
    const float* ri_shift  = (const float*)d_in[4];
    const float* freq_gain = (const float*)d_in[5];
    const float* sw        = (const float*)d_in[6];
    float* out = (float*)d_out;
    unsigned short* wt = (unsigned short*)d_ws;   // 32*9*32*512*2 = 9,437,184 B

    hipMemsetAsync(d_out, 0, (size_t)out_size, stream);   // atomics accumulate into zeroed out
    hipLaunchKernelGGL(wtoep_pack, dim3(32, 9), dim3(256), 0, stream, sw, wt);
    hipLaunchKernelGGL(wavelet_synth_v5, dim3(32, 32), dim3(256), 0, stream,
                       coeffs, rows, cols, ri_scale, ri_shift, freq_gain, wt, out);
}

// Round 2
// 398.151 us; speedup vs baseline: 1.1488x; 1.0361x over previous
//
#include <hip/hip_runtime.h>

typedef __attribute__((ext_vector_type(8))) short short8;
typedef __attribute__((ext_vector_type(4))) float f32x4;

#define C_ 32
#define T_ 2048
#define K_ 129

__device__ __forceinline__ unsigned int bfround(float f) {
    unsigned int u = __float_as_uint(f);
    return u + 0x7fffu + ((u >> 16) & 1u);   // RNE bf16 in high 16 bits
}

// barrier WITHOUT vmcnt drain: LDS visibility only, global prefetch stays in flight
#define BARRIER_LDS() do {                                   \
    __builtin_amdgcn_sched_barrier(0);                       \
    asm volatile("s_waitcnt lgkmcnt(0)" ::: "memory");       \
    __builtin_amdgcn_s_barrier();                            \
    __builtin_amdgcn_sched_barrier(0);                       \
} while (0)

// ---- k0: pack Toeplitz-W A-fragments into d_ws ----
// A_{c,d,iq,igl}[m, k=(i2,tl)] = bf16( sw[c, iq*8+igl*2+i2, 16d+64+m-tl] ), j-OOB = 0
__global__ __launch_bounds__(256) void wtoep_pack(
    const float* __restrict__ sw, unsigned short* __restrict__ wt)
{
    const int c = blockIdx.x, dd = blockIdx.y;     // 32 x 9
    const int t = threadIdx.x, l = t & 63, fw = t >> 6;
    const int m = l & 15, qb = (l >> 4) & 1, i2 = (l >> 5) & 1;
    const int d = dd - 4;
    for (int fr = fw; fr < 32; fr += 4) {          // fr = iq*4 + igl
        const int iq = fr >> 2, igl = fr & 3;
        const int i = iq * 8 + igl * 2 + i2;
        unsigned short v[8];
        #pragma unroll
        for (int e = 0; e < 8; ++e) {
            const int tl = 8 * qb + e;
            const int j = 16 * d + 64 + m - tl;
            const float wv = (j >= 0 && j <= 128) ? sw[(c * 64 + i) * K_ + j] : 0.f;
            v[e] = (unsigned short)(bfround(wv) >> 16);
        }
        *(short8*)(wt + (((c * 9 + dd) * 32 + fr) * 64 + l) * 8) = *(short8*)v;
    }
}

// ---- k2: 8-tile scatter MFMA conv with register prefetch ----
// Block owns z-tiles [g0, g0+8) of one channel. Coeffs read exactly once,
// next-iq loads issued before the barrier (no vmcnt drain) so they complete
// under the compute phase. Scatters acc[vi+d] to out via f32 atomics.
__global__ __launch_bounds__(256, 2) void wavelet_synth_v6(
    const float* __restrict__ coeffs, const int* __restrict__ rows,
    const int* __restrict__ cols, const float* __restrict__ ri_scale,
    const float* __restrict__ ri_shift, const float* __restrict__ freq_gain,
    const unsigned short* __restrict__ wt, float* __restrict__ out)
{
    // zs: 8 vtiles x 8 il x 16 b rows of 16 tau bf16 padded to 24 -> 49152 B
    // red (aliased after compute): 4 waves x 16 tiles x 64 lanes x 4 f32 = 65536 B
    __shared__ __align__(16) unsigned char smem[65536];
    unsigned short* zs = (unsigned short*)smem;

    const int t  = threadIdx.x;
    const int g0 = blockIdx.x * 8;      // owned z-tiles g0..g0+7
    const int c  = blockIdx.y;
    const int rc = rows[c];
    const int cc = cols[c];

    const int lane = t & 63;
    const int w    = t >> 6;            // wave id = igl
    const int i2   = (lane >> 5) & 1;
    const int qb   = (lane >> 4) & 1;

    // staging decomposition: thread -> (r half, batch, il)
    const int s_r  = t & 1;
    const int s_b  = (t >> 1) & 15;
    const int s_il = (t >> 5) & 7;

    f32x4 acc[16];
    #pragma unroll
    for (int a = 0; a < 16; ++a) acc[a] = (f32x4){0.f, 0.f, 0.f, 0.f};

    float4 pf[16];
    // prologue: prefetch iq=0
    {
        const int i  = s_il;
        const int f  = i & 31;
        const int ri = i >> 5;
        const long row = ((long)(s_b * 2 + ri) * 32 + f) * 35 + rc * 5 + cc;
        const float* src = coeffs + row * T_ + g0 * 16 + s_r * 8;
        #pragma unroll
        for (int vi = 0; vi < 8; ++vi) {
            pf[vi * 2 + 0] = *(const float4*)(src + vi * 16);
            pf[vi * 2 + 1] = *(const float4*)(src + vi * 16 + 4);
        }
    }

    for (int iq = 0; iq < 8; ++iq) {
        const int i = iq * 8 + s_il;
        const int f = i & 31;
        const float inv = __builtin_amdgcn_rcpf(ri_scale[f] + 1e-12f);
        const float Aa  = inv * freq_gain[f];
        const float Bb  = -ri_shift[f] * freq_gain[f];

        BARRIER_LDS();   // previous phase's zs reads complete (consumed by MFMAs)

        // pack prefetched regs -> zs (waits vmcnt via data dependence only)
        #pragma unroll
        for (int vi = 0; vi < 8; ++vi) {
            const float4 x = pf[vi * 2 + 0];
            const float4 y = pf[vi * 2 + 1];
            float vv[8];
            vv[0] = x.x * Aa + Bb; vv[1] = x.y * Aa + Bb;
            vv[2] = x.z * Aa + Bb; vv[3] = x.w * Aa + Bb;
            vv[4] = y.x * Aa + Bb; vv[5] = y.y * Aa + Bb;
            vv[6] = y.z * Aa + Bb; vv[7] = y.w * Aa + Bb;
            unsigned short pk[8];
            #pragma unroll
            for (int e = 0; e < 8; ++e) pk[e] = (unsigned short)(bfround(vv[e]) >> 16);
            *(short8*)(zs + ((vi * 8 + s_il) * 16 + s_b) * 24 + s_r * 8) = *(short8*)pk;
        }

        // issue next-iq prefetch (regs just freed); stays in flight across barrier
        if (iq < 7) {
            const int i1  = (iq + 1) * 8 + s_il;
            const int f1  = i1 & 31;
            const int ri1 = i1 >> 5;
            const long row1 = ((long)(s_b * 2 + ri1) * 32 + f1) * 35 + rc * 5 + cc;
            const float* src1 = coeffs + row1 * T_ + g0 * 16 + s_r * 8;
            #pragma unroll
            for (int vi = 0; vi < 8; ++vi) {
                pf[vi * 2 + 0] = *(const float4*)(src1 + vi * 16);
                pf[vi * 2 + 1] = *(const float4*)(src1 + vi * 16 + 4);
            }
        }

        BARRIER_LDS();   // zs writes visible to all waves

        // compute: hoist d-invariant B-fragments, 9 d-shifts x 8 owned z-tiles
        const unsigned short* wbase = wt + ((c * 9) * 32 + iq * 4 + w) * 512 + lane * 8;
        const unsigned short* zb =
            zs + ((w * 2 + i2) * 16 + (lane & 15)) * 24 + qb * 8;
        short8 bfr[8];
        #pragma unroll
        for (int vi = 0; vi < 8; ++vi)
            bfr[vi] = *(const short8*)(zb + vi * (8 * 16 * 24));
        #pragma unroll
        for (int d = 0; d < 9; ++d) {
            const short8 afrag = *(const short8*)(wbase + d * 32 * 512);
            #pragma unroll
            for (int vi = 0; vi < 8; ++vi) {
                acc[vi + d] = __builtin_amdgcn_mfma_f32_16x16x32_bf16(
                    afrag, bfr[vi], acc[vi + d], 0, 0, 0);
            }
        }
    }

    // ---- cross-wave reduce + atomic scatter to out ----
    BARRIER_LDS();   // all compute reads of zs done before aliasing overwrite
    float* red = (float*)smem;
    #pragma unroll
    for (int a = 0; a < 16; ++a)
        *(f32x4*)(red + ((w * 16 + a) * 64 + lane) * 4) = acc[a];
    BARRIER_LDS();   // red visible

    {
        const int rb  = t >> 4;          // batch 0..15
        const int tau = t & 15;          // tau within tile
        const int s   = tau >> 2;
        const int rr  = tau & 3;
        float* obase = out + ((long)rb * C_ + c) * T_ + tau;
        #pragma unroll
        for (int a = 0; a < 16; ++a) {
            const int o = g0 - 4 + a;    // absolute out tile
            if (o < 0 || o >= 128) continue;
            float sum = 0.f;
            #pragma unroll
            for (int ww = 0; ww < 4; ++ww)
                sum += red[((ww * 16 + a) * 64 + s * 16 + rb) * 4 + rr];
            unsafeAtomicAdd(obase + o * 16, sum);
        }
    }
}

extern "C" void kernel_launch(void* const* d_in, const int* in_sizes, int n_in,
                              void* d_out, int out_size, void* d_ws, size_t ws_size,
                              hipStream_t stream) {
    const float* coeffs    = (const float*)d_in[0];
    const int*   rows      = (const int*)d_in[1];
    const int*   cols      = (const int*)d_in[2];
    const float* ri_scale  = (const float*)d_in[3];
    const float* ri_shift  = (const float*)d_in[4];
    const float* freq_gain = (const float*)d_in[5];
    const float* sw        = (const float*)d_in[6];
    float* out = (float*)d_out;
    unsigned short* wt = (unsigned short*)d_ws;   // 32*9*32*512*2 = 9,437,184 B

    hipMemsetAsync(d_out, 0, (size_t)out_size, stream);   // atomics accumulate into zeroed out
    hipLaunchKernelGGL(wtoep_pack, dim3(32, 9), dim3(256), 0, stream, sw, wt);
    hipLaunchKernelGGL(wavelet_synth_v6, dim3(16, 32), dim3(256), 0, stream,
                       coeffs, rows, cols, ri_scale, ri_shift, freq_gain, wt, out);
}

// Round 3
// 392.593 us; speedup vs baseline: 1.1650x; 1.0142x over previous
//
#include <hip/hip_runtime.h>

typedef __attribute__((ext_vector_type(8))) short short8;
typedef __attribute__((ext_vector_type(4))) float f32x4;

#define C_ 32
#define T_ 2048
#define K_ 129

__device__ __forceinline__ unsigned int bfround(float f) {
    unsigned int u = __float_as_uint(f);
    return u + 0x7fffu + ((u >> 16) & 1u);   // RNE bf16 in high 16 bits
}

// barrier WITHOUT vmcnt drain: LDS visibility only, global prefetch stays in flight
#define BARRIER_LDS() do {                                   \
    __builtin_amdgcn_sched_barrier(0);                       \
    asm volatile("s_waitcnt lgkmcnt(0)" ::: "memory");       \
    __builtin_amdgcn_s_barrier();                            \
    __builtin_amdgcn_sched_barrier(0);                       \
} while (0)

// ---- k0: pack Toeplitz-W A-fragments into d_ws ----
__global__ __launch_bounds__(256) void wtoep_pack(
    const float* __restrict__ sw, unsigned short* __restrict__ wt)
{
    const int c = blockIdx.x, dd = blockIdx.y, bz = blockIdx.z;   // 32 x 9 x 2
    const int t = threadIdx.x, l = t & 63, fw = t >> 6;
    const int m = l & 15, qb = (l >> 4) & 1, i2 = (l >> 5) & 1;
    const int d = dd - 4;
    for (int fr = fw + 16 * bz; fr < 16 * bz + 16; fr += 4) {     // fr = iq*4 + igl
        const int iq = fr >> 2, igl = fr & 3;
        const int i = iq * 8 + igl * 2 + i2;
        unsigned short v[8];
        #pragma unroll
        for (int e = 0; e < 8; ++e) {
            const int tl = 8 * qb + e;
            const int j = 16 * d + 64 + m - tl;
            const float wv = (j >= 0 && j <= 128) ? sw[(c * 64 + i) * K_ + j] : 0.f;
            v[e] = (unsigned short)(bfround(wv) >> 16);
        }
        *(short8*)(wt + (((c * 9 + dd) * 32 + fr) * 64 + l) * 8) = *(short8*)v;
    }
}

// XOR-swizzled z row addressing: row R (0..1023), half (0/1) -> ushort index.
// 32 B rows, swizzle flips byte-bits 4..6 by (R>>2)&7: 16B-aligned, vi-invariant
// (R+128 keeps (R>>2)&7), uniform 8-lane/4-bank-window for both write & read maps.
__device__ __forceinline__ int zidx(int R, int half) {
    return (R * 16 + half * 8) ^ (((R >> 2) & 7) << 3);
}

// ---- k2: 8-tile scatter MFMA conv, double-buffered, 1 barrier per phase ----
__global__ __launch_bounds__(256, 2) void wavelet_synth_v7(
    const float* __restrict__ coeffs, const int* __restrict__ rows,
    const int* __restrict__ cols, const float* __restrict__ ri_scale,
    const float* __restrict__ ri_shift, const float* __restrict__ freq_gain,
    const unsigned short* __restrict__ wt, float* __restrict__ out)
{
    // two z buffers of 1024 rows x 32 B = 32768 B each -> 65536 B total
    // red (aliased after compute): 4 waves x 16 tiles x 64 lanes x 4 f32 = 65536 B
    __shared__ __align__(16) unsigned char smem[65536];
    unsigned short* const zs0 = (unsigned short*)smem;
    unsigned short* const zs1 = zs0 + 16384;

    const int t  = threadIdx.x;
    const int g0 = blockIdx.x * 8;      // owned z-tiles g0..g0+7
    const int c  = blockIdx.y;
    const int rc = rows[c];
    const int cc = cols[c];

    const int lane = t & 63;
    const int w    = t >> 6;            // wave id = igl
    const int i2   = (lane >> 5) & 1;
    const int qb   = (lane >> 4) & 1;

    // staging decomposition: thread -> (r half, batch, il)
    const int s_r  = t & 1;
    const int s_b  = (t >> 1) & 15;
    const int s_il = (t >> 5) & 7;

    const int wr_off = zidx(s_il * 16 + s_b, s_r);                  // vi-invariant
    const int rd_off = zidx((w * 2 + i2) * 16 + (lane & 15), qb);   // vi-invariant

    f32x4 acc[16];
    #pragma unroll
    for (int a = 0; a < 16; ++a) acc[a] = (f32x4){0.f, 0.f, 0.f, 0.f};

    float4 pf[16];

#define LOADPF(J) do {                                                        \
    const int i_ = (J) * 8 + s_il;                                            \
    const int f_ = i_ & 31, ri_ = i_ >> 5;                                    \
    const long row_ = ((long)(s_b * 2 + ri_) * 32 + f_) * 35 + rc * 5 + cc;   \
    const float* src_ = coeffs + row_ * T_ + g0 * 16 + s_r * 8;               \
    _Pragma("unroll")                                                         \
    for (int vi = 0; vi < 8; ++vi) {                                          \
        pf[vi * 2 + 0] = *(const float4*)(src_ + vi * 16);                    \
        pf[vi * 2 + 1] = *(const float4*)(src_ + vi * 16 + 4);                \
    }                                                                         \
} while (0)

#define PACK(J, DST) do {                                                     \
    const int i_ = (J) * 8 + s_il;                                            \
    const int f_ = i_ & 31;                                                   \
    const float inv_ = __builtin_amdgcn_rcpf(ri_scale[f_] + 1e-12f);          \
    const float Aa_  = inv_ * freq_gain[f_];                                  \
    const float Bb_  = -ri_shift[f_] * freq_gain[f_];                         \
    _Pragma("unroll")                                                         \
    for (int vi = 0; vi < 8; ++vi) {                                          \
        const float4 x_ = pf[vi * 2 + 0];                                     \
        const float4 y_ = pf[vi * 2 + 1];                                     \
        float vv_[8];                                                         \
        vv_[0] = x_.x * Aa_ + Bb_; vv_[1] = x_.y * Aa_ + Bb_;                 \
        vv_[2] = x_.z * Aa_ + Bb_; vv_[3] = x_.w * Aa_ + Bb_;                 \
        vv_[4] = y_.x * Aa_ + Bb_; vv_[5] = y_.y * Aa_ + Bb_;                 \
        vv_[6] = y_.z * Aa_ + Bb_; vv_[7] = y_.w * Aa_ + Bb_;                 \
        unsigned short pk_[8];                                                \
        _Pragma("unroll")                                                     \
        for (int e = 0; e < 8; ++e) pk_[e] = (unsigned short)(bfround(vv_[e]) >> 16); \
        *(short8*)((DST) + wr_off + vi * 2048) = *(short8*)pk_;               \
    }                                                                         \
} while (0)

    // prologue: fill buffer 0 with iq=0, prefetch iq=1
    LOADPF(0);
    PACK(0, zs0);
    LOADPF(1);

    unsigned short* zcur = zs0;
    unsigned short* znxt = zs1;

    for (int iq = 0; iq < 8; ++iq) {
        BARRIER_LDS();   // zcur writes visible; prefetch loads stay in flight

        // compute from zcur: hoist d-invariant B-fragments, 9 d x 8 vi
        const unsigned short* wbase = wt + ((c * 9) * 32 + iq * 4 + w) * 512 + lane * 8;
        const unsigned short* zb = zcur + rd_off;
        short8 bfr[8];
        #pragma unroll
        for (int vi = 0; vi < 8; ++vi)
            bfr[vi] = *(const short8*)(zb + vi * 2048);
        #pragma unroll
        for (int d = 0; d < 9; ++d) {
            const short8 afrag = *(const short8*)(wbase + d * 32 * 512);
            #pragma unroll
            for (int vi = 0; vi < 8; ++vi) {
                acc[vi + d] = __builtin_amdgcn_mfma_f32_16x16x32_bf16(
                    afrag, bfr[vi], acc[vi + d], 0, 0, 0);
            }
        }

        // stage next phase into znxt (consumes pf), then refill pf for iq+2
        if (iq < 7) PACK(iq + 1, znxt);
        if (iq < 6) LOADPF(iq + 2);

        unsigned short* tmp = zcur; zcur = znxt; znxt = tmp;
    }

    // ---- cross-wave reduce + atomic scatter to out ----
    BARRIER_LDS();   // last compute reads done before aliasing overwrite
    float* red = (float*)smem;
    #pragma unroll
    for (int a = 0; a < 16; ++a)
        *(f32x4*)(red + ((w * 16 + a) * 64 + lane) * 4) = acc[a];
    BARRIER_LDS();   // red visible

    {
        const int rb  = t >> 4;          // batch 0..15
        const int tau = t & 15;          // tau within tile
        const int s   = tau >> 2;
        const int rr  = tau & 3;
        float* obase = out + ((long)rb * C_ + c) * T_ + tau;
        #pragma unroll
        for (int a = 0; a < 16; ++a) {
            const int o = g0 - 4 + a;    // absolute out tile
            if (o < 0 || o >= 128) continue;
            float sum = 0.f;
            #pragma unroll
            for (int ww = 0; ww < 4; ++ww)
                sum += red[((ww * 16 + a) * 64 + s * 16 + rb) * 4 + rr];
            unsafeAtomicAdd(obase + o * 16, sum);
        }
    }
#undef LOADPF
#undef PACK
}

extern "C" void kernel_launch(void* const* d_in, const int* in_sizes, int n_in,
                              void* d_out, int out_size, void* d_ws, size_t ws_size,
                              hipStream_t stream) {
    const float* coeffs    = (const float*)d_in[0];
    const int*   rows      = (const int*)d_in[1];
    const int*   cols      = (const int*)d_in[2];
    const float* ri_scale  = (const float*)d_in[3];
    const float* ri_shift  = (const float*)d_in[4];
    const float* freq_gain = (const float*)d_in[5];
    const float* sw        = (const float*)d_in[6];
    float* out = (float*)d_out;
    unsigned short* wt = (unsigned short*)d_ws;   // 32*9*32*512*2 = 9,437,184 B

    hipMemsetAsync(d_out, 0, (size_t)out_size, stream);   // atomics accumulate into zeroed out
    hipLaunchKernelGGL(wtoep_pack, dim3(32, 9, 2), dim3(256), 0, stream, sw, wt);
    hipLaunchKernelGGL(wavelet_synth_v7, dim3(16, 32), dim3(256), 0, stream,
                       coeffs, rows, cols, ri_scale, ri_shift, freq_gain, wt, out);
}